// Round 1
// baseline (1567.146 us; speedup 1.0000x reference)
//
#include <hip/hip_runtime.h>
#include <math.h>

#define BATCH 256

// x[256][P] -> xt[P][256], 64x64 LDS tiles
__global__ __launch_bounds__(256) void transpose_kernel(
    const float* __restrict__ x, float* __restrict__ xt, int P) {
  __shared__ float tile[64][65];
  int p0 = blockIdx.x * 64, b0 = blockIdx.y * 64;
  int tx = threadIdx.x & 63, ty = threadIdx.x >> 6;  // tx: 0..63, ty: 0..3
#pragma unroll
  for (int r = 0; r < 64; r += 4) {
    int pp = p0 + tx;
    if (pp < P) tile[tx][ty + r] = x[(size_t)(b0 + ty + r) * (size_t)P + pp];
  }
  __syncthreads();
#pragma unroll
  for (int r = 0; r < 64; r += 4) {
    int pl = ty + r, pp = p0 + pl;
    if (pp < P) xt[(size_t)pp * BATCH + b0 + tx] = tile[pl][tx];
  }
}

// Direct 4D conv + bias + relu on batch-innermost layout.
// in : [CIN][TI][TI][TI][TI][256],  out: [COUT][WO][WO][WO][WO][256]
// weights: [COUT][CIN][KK][KK][KK][KK] staged in LDS.
// One block (256 threads, lane=b) per output (t,d,h) position; each thread
// computes acc[COUT][WO] (full w-row, all output channels).
template <int CIN, int COUT, int KK, int TI>
__global__ __launch_bounds__(256) void conv_relu(
    const float* __restrict__ xin, const float* __restrict__ wgt,
    const float* __restrict__ bias, float* __restrict__ out) {
  constexpr int WO = TI - KK + 1;
  constexpr int sH = TI * BATCH, sD = TI * TI * BATCH, sT = TI * TI * TI * BATCH,
                sC = TI * TI * TI * TI * BATCH;
  constexpr int oH = WO * BATCH, oD = WO * WO * BATCH, oT = WO * WO * WO * BATCH,
                oC = WO * WO * WO * WO * BATCH;
  constexpr int NW = COUT * CIN * KK * KK * KK * KK;

  __shared__ float wl[NW];
  for (int i = threadIdx.x; i < NW; i += 256) wl[i] = wgt[i];
  __syncthreads();

  const int p = blockIdx.x;
  const int t = p / (WO * WO);
  const int rem = p - t * WO * WO;
  const int d = rem / WO;
  const int h = rem % WO;
  const int b = threadIdx.x;

  float acc[COUT][WO];
#pragma unroll
  for (int co = 0; co < COUT; co++) {
    float bv = bias[co];
#pragma unroll
    for (int j = 0; j < WO; j++) acc[co][j] = bv;
  }

#pragma unroll 1
  for (int ci = 0; ci < CIN; ci++)
#pragma unroll 1
    for (int kt = 0; kt < KK; kt++)
#pragma unroll 1
      for (int kd = 0; kd < KK; kd++)
#pragma unroll 1
        for (int kh = 0; kh < KK; kh++) {
          const float* row =
              xin + ci * sC + (t + kt) * sT + (d + kd) * sD + (h + kh) * sH + b;
          float xv[TI];
#pragma unroll
          for (int j = 0; j < TI; j++) xv[j] = row[j * BATCH];  // coalesced: lane=b
#pragma unroll
          for (int kw = 0; kw < KK; kw++) {
#pragma unroll
            for (int co = 0; co < COUT; co++) {
              const float wv =
                  wl[((((co * CIN + ci) * KK + kt) * KK + kd) * KK + kh) * KK + kw];
#pragma unroll
              for (int j = 0; j < WO; j++)
                acc[co][j] = fmaf(xv[j + kw], wv, acc[co][j]);
            }
          }
        }

#pragma unroll
  for (int co = 0; co < COUT; co++)
#pragma unroll
    for (int j = 0; j < WO; j++) {
      float v = acc[co][j];
      v = v > 0.f ? v : 0.f;
      out[co * oC + t * oT + d * oD + h * oH + j * BATCH + b] = v;
    }
}

// h5 is [1280][256] (k-major, matches reshape order co,t,d,h,w). One block per
// output neuron o; thread = batch lane. out: [33][256].
__global__ __launch_bounds__(256) void fc1_kernel(
    const float* __restrict__ h, const float* __restrict__ w,
    const float* __restrict__ bias, float* __restrict__ out) {
  const int o = blockIdx.x, b = threadIdx.x;
  const float* wr = w + o * 1280;
  float a0 = 0.f, a1 = 0.f, a2 = 0.f, a3 = 0.f;
#pragma unroll 4
  for (int k = 0; k < 1280; k += 4) {
    a0 = fmaf(h[(k + 0) * BATCH + b], wr[k + 0], a0);
    a1 = fmaf(h[(k + 1) * BATCH + b], wr[k + 1], a1);
    a2 = fmaf(h[(k + 2) * BATCH + b], wr[k + 2], a2);
    a3 = fmaf(h[(k + 3) * BATCH + b], wr[k + 3], a3);
  }
  float acc = (a0 + a1) + (a2 + a3) + bias[o];
  out[o * BATCH + b] = acc > 0.f ? acc : 0.f;
}

// r: [33][256] -> d_out[256] = sigmoid(w.r + b)
__global__ __launch_bounds__(256) void fc2_kernel(
    const float* __restrict__ r, const float* __restrict__ w,
    const float* __restrict__ bias, float* __restrict__ out) {
  const int b = threadIdx.x;
  float acc = bias[0];
#pragma unroll
  for (int o = 0; o < 33; o++) acc = fmaf(r[o * BATCH + b], w[o], acc);
  out[b] = 1.f / (1.f + expf(-acc));
}

extern "C" void kernel_launch(void* const* d_in, const int* in_sizes, int n_in,
                              void* d_out, int out_size, void* d_ws, size_t ws_size,
                              hipStream_t stream) {
  const float* x    = (const float*)d_in[0];
  const float* w1   = (const float*)d_in[1];
  const float* b1   = (const float*)d_in[2];
  const float* w2   = (const float*)d_in[3];
  const float* b2   = (const float*)d_in[4];
  const float* w3   = (const float*)d_in[5];
  const float* b3   = (const float*)d_in[6];
  const float* w4   = (const float*)d_in[7];
  const float* b4   = (const float*)d_in[8];
  const float* w5   = (const float*)d_in[9];
  const float* b5   = (const float*)d_in[10];
  const float* fc1w = (const float*)d_in[11];
  const float* fc1b = (const float*)d_in[12];
  const float* fc2w = (const float*)d_in[13];
  const float* fc2b = (const float*)d_in[14];
  float* out = (float*)d_out;

  // Workspace layout (floats). Ping-pong two regions:
  //  R0 (offset 0, 26,873,856 fl): xt, then h2, h4, fc1out
  //  R1 (26,873,856 fl, 38,880,000 fl): h1, h3, h5
  // Total 263 MB.
  float* wsf = (float*)d_ws;
  float* R0 = wsf;
  float* R1 = wsf + 26873856;
  float* xt = R0;
  float* h1 = R1;
  float* h2 = R0;
  float* h3 = R1;
  float* h4 = R0;
  float* h5 = R1;
  float* fo = R0;

  const int P = 104976;  // 18^4
  transpose_kernel<<<dim3((P + 63) / 64, 4), 256, 0, stream>>>(x, xt, P);

  conv_relu<1, 3, 4, 18><<<15 * 15 * 15, 256, 0, stream>>>(xt, w1, b1, h1);
  conv_relu<3, 3, 4, 15><<<12 * 12 * 12, 256, 0, stream>>>(h1, w2, b2, h2);
  conv_relu<3, 4, 4, 12><<<9 * 9 * 9, 256, 0, stream>>>(h2, w3, b3, h3);
  conv_relu<4, 5, 4, 9><<<6 * 6 * 6, 256, 0, stream>>>(h3, w4, b4, h4);
  conv_relu<5, 5, 3, 6><<<4 * 4 * 4, 256, 0, stream>>>(h4, w5, b5, h5);

  fc1_kernel<<<33, 256, 0, stream>>>(h5, fc1w, fc1b, fo);
  fc2_kernel<<<1, 256, 0, stream>>>(fo, fc2w, fc2b, out);
}